// Round 3
// baseline (718.303 us; speedup 1.0000x reference)
//
#include <hip/hip_runtime.h>
#include <hip/hip_bf16.h>

typedef __attribute__((ext_vector_type(8))) short bf16x8;
typedef __attribute__((ext_vector_type(4))) float f32x4;

#define LOG2E  1.4426950408889634f
#define QSCALE 0.08838834764831845f   // 1/sqrt(128)

__device__ __forceinline__ short f2bf(float f) {
  union { float f; unsigned u; } x;
  x.f = f;
  unsigned u = x.u;
  u += 0x7fffu + ((u >> 16) & 1u);   // RNE
  return (short)(u >> 16);
}

__device__ __forceinline__ unsigned packbf(float a, float b) {
  return (unsigned)(unsigned short)f2bf(a) | ((unsigned)(unsigned short)f2bf(b) << 16);
}

__global__ __launch_bounds__(256, 3) void attn_fwd(
    const float* __restrict__ Qg, const float* __restrict__ Kg,
    const float* __restrict__ Vg, float* __restrict__ Og)
{
  // XOR-swizzled tiles: 16B chunk index ^= (row&7)
  __shared__ short K_lds[64 * 128];   // [kv][d]   16 KB
  __shared__ short V_T[128 * 64];     // [d][kv]   16 KB

  const int tid  = threadIdx.x;
  const int lane = tid & 63;
  const int wave = tid >> 6;
  const int g    = lane >> 4;   // 0..3
  const int lo   = lane & 15;   // 0..15
  const int lo7  = lo & 7;

  // heavy-first: qt descending so 32-tile causal blocks start first
  const int bid = blockIdx.x;
  const int qt  = 15 - (bid >> 6);
  const int bh  = bid & 63;
  const int q0  = qt * 128;

  const size_t base = (size_t)bh * 2048 * 128;
  const float* Qb = Qg + base;
  const float* Kb = Kg + base;
  const float* Vb = Vg + base;
  float*       Ob = Og + base;

  // --- Q fragments (scaled). B-frag role for swapped QK^T: col=lo, k=g*8+j ---
  bf16x8 qf[2][4];
  #pragma unroll
  for (int mt = 0; mt < 2; ++mt) {
    const int row = q0 + wave * 32 + mt * 16 + lo;
    const float* qr = Qb + (size_t)row * 128 + g * 8;
    #pragma unroll
    for (int kb = 0; kb < 4; ++kb) {
      f32x4 a = *(const f32x4*)(qr + kb * 32);
      f32x4 b = *(const f32x4*)(qr + kb * 32 + 4);
      bf16x8 w;
      #pragma unroll
      for (int j = 0; j < 4; ++j) { w[j] = f2bf(a[j] * QSCALE); w[4 + j] = f2bf(b[j] * QSCALE); }
      qf[mt][kb] = w;
    }
  }

  float m_st[2] = {-3.0e38f, -3.0e38f};
  float l_st[2] = {0.0f, 0.0f};
  f32x4 o_acc[2][8];   // O^T: col=q(lo), row d = nd*16 + g*4 + r
  #pragma unroll
  for (int mt = 0; mt < 2; ++mt)
    #pragma unroll
    for (int nd = 0; nd < 8; ++nd) o_acc[mt][nd] = (f32x4){0.f, 0.f, 0.f, 0.f};

  const bool b1 = (g >> 1) & 1;
  const bool b0 = g & 1;

  const int ntiles = 2 * (qt + 1);

  // ---- T14 prefetch registers (fp32; converted at writeback) ----
  f32x4 kpa[4], kpb[4];     // K: 4 chunks x 8 floats
  float vp[4][4][2];        // V: [i][j][pair]
  const int vd   = tid & 31;
  const int vprb = tid >> 5;

  // prologue: issue tile-0 loads
  #pragma unroll
  for (int i = 0; i < 4; ++i) {
    const int idx = i * 256 + tid;
    const int kr = idx >> 4, dc16 = idx & 15;
    const float* src = Kb + (size_t)kr * 128 + dc16 * 8;
    kpa[i] = *(const f32x4*)src;
    kpb[i] = *(const f32x4*)(src + 4);
  }
  #pragma unroll
  for (int i = 0; i < 4; ++i) {
    const int pr = vprb + i * 8;
    const float* v0 = Vb + (size_t)(2 * pr) * 128 + vd;
    #pragma unroll
    for (int j = 0; j < 4; ++j) { vp[i][j][0] = v0[j * 32]; vp[i][j][1] = v0[j * 32 + 128]; }
  }

  for (int t = 0; t < ntiles; ++t) {
    const int kv0 = t * 64;

    // ---- writeback prefetched regs -> LDS (vmcnt wait lands here) ----
    #pragma unroll
    for (int i = 0; i < 4; ++i) {
      const int idx = i * 256 + tid;
      const int kr = idx >> 4, dc16 = idx & 15;
      bf16x8 w;
      #pragma unroll
      for (int j = 0; j < 4; ++j) { w[j] = f2bf(kpa[i][j]); w[4 + j] = f2bf(kpb[i][j]); }
      *(bf16x8*)&K_lds[kr * 128 + ((dc16 ^ (kr & 7)) * 8)] = w;
    }
    #pragma unroll
    for (int i = 0; i < 4; ++i) {
      const int pr = vprb + i * 8;
      #pragma unroll
      for (int j = 0; j < 4; ++j) {
        const int row = vd + j * 32;
        const unsigned pk = packbf(vp[i][j][0], vp[i][j][1]);
        *(unsigned*)&V_T[row * 64 + (((pr >> 2) ^ (row & 7)) * 8) + (pr & 3) * 2] = pk;
      }
    }
    __syncthreads();   // LDS tile t ready

    // ---- issue tile t+1 loads (latency hides under compute of tile t) ----
    if (t + 1 < ntiles) {
      const int nkv0 = kv0 + 64;
      #pragma unroll
      for (int i = 0; i < 4; ++i) {
        const int idx = i * 256 + tid;
        const int kr = idx >> 4, dc16 = idx & 15;
        const float* src = Kb + (size_t)(nkv0 + kr) * 128 + dc16 * 8;
        kpa[i] = *(const f32x4*)src;
        kpb[i] = *(const f32x4*)(src + 4);
      }
      #pragma unroll
      for (int i = 0; i < 4; ++i) {
        const int pr = vprb + i * 8;
        const float* v0 = Vb + (size_t)(nkv0 + 2 * pr) * 128 + vd;
        #pragma unroll
        for (int j = 0; j < 4; ++j) { vp[i][j][0] = v0[j * 32]; vp[i][j][1] = v0[j * 32 + 128]; }
      }
    }

    if (kv0 <= q0 + wave * 32 + 31) {   // wave has unmasked work in this tile
      // ---- swapped QK^T: S^T = mfma(K, Q); lane holds S[q=lo][kv=nb*16+g*4+r] ----
      f32x4 s[2][4];
      #pragma unroll
      for (int mt = 0; mt < 2; ++mt)
        #pragma unroll
        for (int nb = 0; nb < 4; ++nb) s[mt][nb] = (f32x4){0.f, 0.f, 0.f, 0.f};

      __builtin_amdgcn_s_setprio(1);
      #pragma unroll
      for (int nb = 0; nb < 4; ++nb) {
        #pragma unroll
        for (int kb = 0; kb < 4; ++kb) {
          bf16x8 kf = *(const bf16x8*)&K_lds[(nb * 16 + lo) * 128 + (((kb * 4 + g) ^ lo7) * 8)];
          s[0][nb] = __builtin_amdgcn_mfma_f32_16x16x32_bf16(kf, qf[0][kb], s[0][nb], 0, 0, 0);
          s[1][nb] = __builtin_amdgcn_mfma_f32_16x16x32_bf16(kf, qf[1][kb], s[1][nb], 0, 0, 0);
        }
      }
      __builtin_amdgcn_s_setprio(0);

      // ---- causal mask ----
      if (kv0 + 63 > q0 + wave * 32) {
        #pragma unroll
        for (int mt = 0; mt < 2; ++mt) {
          const int qrow = q0 + wave * 32 + mt * 16 + lo;
          #pragma unroll
          for (int nb = 0; nb < 4; ++nb) {
            const int kvb = kv0 + nb * 16 + g * 4;
            #pragma unroll
            for (int r = 0; r < 4; ++r)
              if (kvb + r > qrow) s[mt][nb][r] = -1.0e30f;
          }
        }
      }

      // ---- online softmax (scalar per lane) + P -> PV B-frags in registers ----
      bf16x8 pfrag[2][2];
      #pragma unroll
      for (int mt = 0; mt < 2; ++mt) {
        float tm = s[mt][0][0];
        #pragma unroll
        for (int nb = 0; nb < 4; ++nb)
          #pragma unroll
          for (int r = 0; r < 4; ++r) tm = fmaxf(tm, s[mt][nb][r]);
        tm = fmaxf(tm, __shfl_xor(tm, 16));
        tm = fmaxf(tm, __shfl_xor(tm, 32));
        const float mn = fmaxf(m_st[mt], tm);
        const float alpha = __builtin_amdgcn_exp2f((m_st[mt] - mn) * LOG2E);
        m_st[mt] = mn;

        float p[4][4];
        float ps = 0.0f;
        #pragma unroll
        for (int nb = 0; nb < 4; ++nb)
          #pragma unroll
          for (int r = 0; r < 4; ++r) {
            p[nb][r] = __builtin_amdgcn_exp2f((s[mt][nb][r] - mn) * LOG2E);
            ps += p[nb][r];
          }
        ps += __shfl_xor(ps, 16);
        ps += __shfl_xor(ps, 32);
        l_st[mt] = l_st[mt] * alpha + ps;
        #pragma unroll
        for (int nd = 0; nd < 8; ++nd)
          #pragma unroll
          for (int r = 0; r < 4; ++r) o_acc[mt][nd][r] *= alpha;

        // pack P pairs: pk[n1][n0][w] holds kv pair (n1*32+n0*16+g*4+2w, +1), q=lo
        unsigned pk[2][2][2];
        #pragma unroll
        for (int n1 = 0; n1 < 2; ++n1)
          #pragma unroll
          for (int n0 = 0; n0 < 2; ++n0)
            #pragma unroll
            for (int w = 0; w < 2; ++w)
              pk[n1][n0][w] = packbf(p[n1 * 2 + n0][2 * w], p[n1 * 2 + n0][2 * w + 1]);

        // butterfly: swap reg-bit n0 <-> lane-bit b1 (xor32), then rb <-> b0 (xor16)
        #pragma unroll
        for (int n1 = 0; n1 < 2; ++n1) {
          unsigned q2[2][2];
          #pragma unroll
          for (int w = 0; w < 2; ++w) {
            unsigned a = pk[n1][0][w], b = pk[n1][1][w];
            unsigned recv = __shfl_xor(b1 ? a : b, 32);
            unsigned r0 = b1 ? recv : a;
            unsigned r1 = b1 ? b : recv;
            unsigned recv2 = __shfl_xor(b0 ? r0 : r1, 16);
            q2[0][w] = b0 ? recv2 : r0;
            q2[1][w] = b0 ? r1 : recv2;
          }
          union { bf16x8 v; unsigned u[4]; } fb;
          fb.u[0] = q2[0][0]; fb.u[1] = q2[0][1]; fb.u[2] = q2[1][0]; fb.u[3] = q2[1][1];
          pfrag[mt][n1] = fb.v;   // B-frag: P^T[kv = n1*32 + g*8 + j][q = lo]
        }
      }

      // ---- PV: O^T += mfma(A=V^T, B=P^T) ----
      __builtin_amdgcn_s_setprio(1);
      #pragma unroll
      for (int kb2 = 0; kb2 < 2; ++kb2) {
        #pragma unroll
        for (int nd = 0; nd < 8; ++nd) {
          bf16x8 vf = *(const bf16x8*)&V_T[(nd * 16 + lo) * 64 + (((kb2 * 4 + g) ^ lo7) * 8)];
          o_acc[0][nd] = __builtin_amdgcn_mfma_f32_16x16x32_bf16(vf, pfrag[0][kb2], o_acc[0][nd], 0, 0, 0);
          o_acc[1][nd] = __builtin_amdgcn_mfma_f32_16x16x32_bf16(vf, pfrag[1][kb2], o_acc[1][nd], 0, 0, 0);
        }
      }
      __builtin_amdgcn_s_setprio(0);
    }

    __syncthreads();   // all waves done reading LDS before next writeback
  }

  // ---- epilogue: O[q][d] = o_acc / l, f32x4 stores ----
  #pragma unroll
  for (int mt = 0; mt < 2; ++mt) {
    const float inv = 1.0f / l_st[mt];
    const int q = q0 + wave * 32 + mt * 16 + lo;
    #pragma unroll
    for (int nd = 0; nd < 8; ++nd) {
      f32x4 o;
      #pragma unroll
      for (int r = 0; r < 4; ++r) o[r] = o_acc[mt][nd][r] * inv;
      *(f32x4*)(Ob + (size_t)q * 128 + nd * 16 + g * 4) = o;
    }
  }
}

extern "C" void kernel_launch(void* const* d_in, const int* in_sizes, int n_in,
                              void* d_out, int out_size, void* d_ws, size_t ws_size,
                              hipStream_t stream) {
  const float* Q = (const float*)d_in[0];
  const float* K = (const float*)d_in[1];
  const float* V = (const float*)d_in[2];
  float* O = (float*)d_out;
  attn_fwd<<<dim3(1024), 256, 0, stream>>>(Q, K, V, O);
}

// Round 4
// 600.987 us; speedup vs baseline: 1.1952x; 1.1952x over previous
//
#include <hip/hip_runtime.h>
#include <hip/hip_bf16.h>

typedef __attribute__((ext_vector_type(8))) short bf16x8;
typedef __attribute__((ext_vector_type(4))) float f32x4;

#define LOG2E  1.4426950408889634f
#define QSCALE 0.08838834764831845f   // 1/sqrt(128)

__device__ __forceinline__ short f2bf(float f) {
  union { float f; unsigned u; } x;
  x.f = f;
  unsigned u = x.u;
  u += 0x7fffu + ((u >> 16) & 1u);   // RNE
  return (short)(u >> 16);
}

__device__ __forceinline__ unsigned packbf(float a, float b) {
  return (unsigned)(unsigned short)f2bf(a) | ((unsigned)(unsigned short)f2bf(b) << 16);
}

__global__ __launch_bounds__(256, 4) void attn_fwd(
    const float* __restrict__ Qg, const float* __restrict__ Kg,
    const float* __restrict__ Vg, float* __restrict__ Og)
{
  // XOR-swizzled tiles: 16B chunk index ^= (row&7)
  __shared__ short K_lds[64 * 128];   // [kv][d]   16 KB
  __shared__ short V_T[128 * 64];     // [d][kv]   16 KB

  const int tid  = threadIdx.x;
  const int lane = tid & 63;
  const int wave = tid >> 6;
  const int g    = lane >> 4;   // 0..3
  const int lo   = lane & 15;   // 0..15
  const int lo7  = lo & 7;

  // Work-balanced, head-clustered mapping: CU c receives blocks c, c+256,
  // c+512, c+768 -> same head h, qt set {15-j, 11-j?} with constant work sum 34,
  // so every CU gets equal causal work AND its 4 blocks share one K/V stream.
  const int d_  = blockIdx.x;
  const int bh  = d_ & 63;
  const int j_  = (d_ >> 6) & 7;
  const int qt  = (d_ < 512) ? (15 - j_) : j_;
  const int q0  = qt * 128;

  const size_t base = (size_t)bh * 2048 * 128;
  const float* Qb = Qg + base;
  const float* Kb = Kg + base;
  const float* Vb = Vg + base;
  float*       Ob = Og + base;

  // --- Q fragments (scaled). B-frag role for swapped QK^T: col=lo, k=g*8+j ---
  bf16x8 qf[2][4];
  #pragma unroll
  for (int mt = 0; mt < 2; ++mt) {
    const int row = q0 + wave * 32 + mt * 16 + lo;
    const float* qr = Qb + (size_t)row * 128 + g * 8;
    #pragma unroll
    for (int kb = 0; kb < 4; ++kb) {
      f32x4 a = *(const f32x4*)(qr + kb * 32);
      f32x4 b = *(const f32x4*)(qr + kb * 32 + 4);
      bf16x8 w;
      #pragma unroll
      for (int jj = 0; jj < 4; ++jj) { w[jj] = f2bf(a[jj] * QSCALE); w[4 + jj] = f2bf(b[jj] * QSCALE); }
      qf[mt][kb] = w;
    }
  }

  // per-lane scalar softmax state (q = lo within each mt tile)
  float m_st[2] = {-3.0e38f, -3.0e38f};
  float l_st[2] = {0.0f, 0.0f};
  f32x4 o_acc[2][8];   // O^T: col=q(lo), row d = nd*16 + g*4 + r
  #pragma unroll
  for (int mt = 0; mt < 2; ++mt)
    #pragma unroll
    for (int nd = 0; nd < 8; ++nd) o_acc[mt][nd] = (f32x4){0.f, 0.f, 0.f, 0.f};

  const bool b1 = (g >> 1) & 1;
  const bool b0 = g & 1;

  const int kv_end = q0 + 128;
  for (int kv0 = 0; kv0 < kv_end; kv0 += 64) {
    __syncthreads();

    // ---- stage K tile: fp32 -> bf16, row-major [kv][128], swizzled chunks ----
    #pragma unroll
    for (int i = 0; i < 4; ++i) {
      const int idx  = i * 256 + tid;       // 1024 chunks of 8 floats
      const int kr   = idx >> 4;            // kv row 0..63
      const int dc16 = idx & 15;            // 16B chunk 0..15
      const float* src = Kb + (size_t)(kv0 + kr) * 128 + dc16 * 8;
      f32x4 a = *(const f32x4*)src;
      f32x4 b = *(const f32x4*)(src + 4);
      bf16x8 w;
      #pragma unroll
      for (int jj = 0; jj < 4; ++jj) { w[jj] = f2bf(a[jj]); w[4 + jj] = f2bf(b[jj]); }
      *(bf16x8*)&K_lds[kr * 128 + ((dc16 ^ (kr & 7)) * 8)] = w;
    }
    // ---- stage V transposed [d][kv], pair-packed b32, swizzled chunks ----
    {
      const int d   = tid & 31;
      const int prb = tid >> 5;
      #pragma unroll
      for (int i = 0; i < 4; ++i) {
        const int pr = prb + i * 8;         // kv pair 0..31
        const float* v0 = Vb + (size_t)(kv0 + 2 * pr) * 128 + d;
        #pragma unroll
        for (int jj = 0; jj < 4; ++jj) {
          const int row = d + jj * 32;
          const unsigned pk = packbf(v0[jj * 32], v0[jj * 32 + 128]);
          *(unsigned*)&V_T[row * 64 + (((pr >> 2) ^ (row & 7)) * 8) + (pr & 3) * 2] = pk;
        }
      }
    }
    __syncthreads();

    if (kv0 > q0 + wave * 32 + 31) continue;   // wave fully masked for this tile

    // ---- swapped QK^T: S^T = mfma(K, Q); lane holds S[q=lo][kv=nb*16+g*4+r] ----
    f32x4 s[2][4];
    #pragma unroll
    for (int mt = 0; mt < 2; ++mt)
      #pragma unroll
      for (int nb = 0; nb < 4; ++nb) s[mt][nb] = (f32x4){0.f, 0.f, 0.f, 0.f};

    __builtin_amdgcn_s_setprio(1);
    #pragma unroll
    for (int nb = 0; nb < 4; ++nb) {
      #pragma unroll
      for (int kb = 0; kb < 4; ++kb) {
        bf16x8 kf = *(const bf16x8*)&K_lds[(nb * 16 + lo) * 128 + (((kb * 4 + g) ^ lo7) * 8)];
        s[0][nb] = __builtin_amdgcn_mfma_f32_16x16x32_bf16(kf, qf[0][kb], s[0][nb], 0, 0, 0);
        s[1][nb] = __builtin_amdgcn_mfma_f32_16x16x32_bf16(kf, qf[1][kb], s[1][nb], 0, 0, 0);
      }
    }
    __builtin_amdgcn_s_setprio(0);

    // ---- causal mask ----
    if (kv0 + 63 > q0 + wave * 32) {
      #pragma unroll
      for (int mt = 0; mt < 2; ++mt) {
        const int qrow = q0 + wave * 32 + mt * 16 + lo;
        #pragma unroll
        for (int nb = 0; nb < 4; ++nb) {
          const int kvb = kv0 + nb * 16 + g * 4;
          #pragma unroll
          for (int r = 0; r < 4; ++r)
            if (kvb + r > qrow) s[mt][nb][r] = -1.0e30f;
        }
      }
    }

    // ---- online softmax (scalar per lane) + P -> PV B-frags in registers ----
    bf16x8 pfrag[2][2];
    #pragma unroll
    for (int mt = 0; mt < 2; ++mt) {
      float tm = s[mt][0][0];
      #pragma unroll
      for (int nb = 0; nb < 4; ++nb)
        #pragma unroll
        for (int r = 0; r < 4; ++r) tm = fmaxf(tm, s[mt][nb][r]);
      tm = fmaxf(tm, __shfl_xor(tm, 16));
      tm = fmaxf(tm, __shfl_xor(tm, 32));
      const float mn = fmaxf(m_st[mt], tm);
      const float alpha = __builtin_amdgcn_exp2f((m_st[mt] - mn) * LOG2E);
      m_st[mt] = mn;

      float p[4][4];
      float ps = 0.0f;
      #pragma unroll
      for (int nb = 0; nb < 4; ++nb)
        #pragma unroll
        for (int r = 0; r < 4; ++r) {
          p[nb][r] = __builtin_amdgcn_exp2f((s[mt][nb][r] - mn) * LOG2E);
          ps += p[nb][r];
        }
      ps += __shfl_xor(ps, 16);
      ps += __shfl_xor(ps, 32);
      l_st[mt] = l_st[mt] * alpha + ps;
      #pragma unroll
      for (int nd = 0; nd < 8; ++nd)
        #pragma unroll
        for (int r = 0; r < 4; ++r) o_acc[mt][nd][r] *= alpha;

      // pack P pairs: pk[n1][n0][w] holds kv pair (n1*32+n0*16+g*4+2w, +1), q=lo
      unsigned pk[2][2][2];
      #pragma unroll
      for (int n1 = 0; n1 < 2; ++n1)
        #pragma unroll
        for (int n0 = 0; n0 < 2; ++n0)
          #pragma unroll
          for (int w = 0; w < 2; ++w)
            pk[n1][n0][w] = packbf(p[n1 * 2 + n0][2 * w], p[n1 * 2 + n0][2 * w + 1]);

      // butterfly: swap reg-bit n0 <-> lane-bit b1 (xor32), then rb <-> b0 (xor16)
      #pragma unroll
      for (int n1 = 0; n1 < 2; ++n1) {
        unsigned q2[2][2];
        #pragma unroll
        for (int w = 0; w < 2; ++w) {
          unsigned a = pk[n1][0][w], b = pk[n1][1][w];
          unsigned recv = __shfl_xor(b1 ? a : b, 32);
          unsigned r0 = b1 ? recv : a;
          unsigned r1 = b1 ? b : recv;
          unsigned recv2 = __shfl_xor(b0 ? r0 : r1, 16);
          q2[0][w] = b0 ? recv2 : r0;
          q2[1][w] = b0 ? r1 : recv2;
        }
        union { bf16x8 v; unsigned u[4]; } fb;
        fb.u[0] = q2[0][0]; fb.u[1] = q2[0][1]; fb.u[2] = q2[1][0]; fb.u[3] = q2[1][1];
        pfrag[mt][n1] = fb.v;   // B-frag: P^T[kv = n1*32 + g*8 + j][q = lo]
      }
    }

    // ---- PV: O^T += mfma(A=V^T, B=P^T) ----
    __builtin_amdgcn_s_setprio(1);
    #pragma unroll
    for (int kb2 = 0; kb2 < 2; ++kb2) {
      #pragma unroll
      for (int nd = 0; nd < 8; ++nd) {
        bf16x8 vf = *(const bf16x8*)&V_T[(nd * 16 + lo) * 64 + (((kb2 * 4 + g) ^ lo7) * 8)];
        o_acc[0][nd] = __builtin_amdgcn_mfma_f32_16x16x32_bf16(vf, pfrag[0][kb2], o_acc[0][nd], 0, 0, 0);
        o_acc[1][nd] = __builtin_amdgcn_mfma_f32_16x16x32_bf16(vf, pfrag[1][kb2], o_acc[1][nd], 0, 0, 0);
      }
    }
    __builtin_amdgcn_s_setprio(0);
  }

  // ---- epilogue: O[q][d] = o_acc / l, f32x4 stores ----
  #pragma unroll
  for (int mt = 0; mt < 2; ++mt) {
    const float inv = 1.0f / l_st[mt];
    const int q = q0 + wave * 32 + mt * 16 + lo;
    #pragma unroll
    for (int nd = 0; nd < 8; ++nd) {
      f32x4 o;
      #pragma unroll
      for (int r = 0; r < 4; ++r) o[r] = o_acc[mt][nd][r] * inv;
      *(f32x4*)(Ob + (size_t)q * 128 + nd * 16 + g * 4) = o;
    }
  }
}

extern "C" void kernel_launch(void* const* d_in, const int* in_sizes, int n_in,
                              void* d_out, int out_size, void* d_ws, size_t ws_size,
                              hipStream_t stream) {
  const float* Q = (const float*)d_in[0];
  const float* K = (const float*)d_in[1];
  const float* V = (const float*)d_in[2];
  float* O = (float*)d_out;
  attn_fwd<<<dim3(1024), 256, 0, stream>>>(Q, K, V, O);
}

// Round 5
// 155.289 us; speedup vs baseline: 4.6256x; 3.8701x over previous
//
#include <hip/hip_runtime.h>
#include <hip/hip_bf16.h>

typedef __attribute__((ext_vector_type(8))) short bf16x8;
typedef __attribute__((ext_vector_type(4))) float f32x4;

#define LOG2E  1.4426950408889634f
#define QSCALE 0.08838834764831845f   // 1/sqrt(128)

__device__ __forceinline__ short f2bf(float f) {
  union { float f; unsigned u; } x;
  x.f = f;
  unsigned u = x.u;
  u += 0x7fffu + ((u >> 16) & 1u);   // RNE
  return (short)(u >> 16);
}

__device__ __forceinline__ unsigned packbf(float a, float b) {
  return (unsigned)(unsigned short)f2bf(a) | ((unsigned)(unsigned short)f2bf(b) << 16);
}

__global__ __launch_bounds__(256, 2) void attn_fwd(
    const float* __restrict__ Qg, const float* __restrict__ Kg,
    const float* __restrict__ Vg, float* __restrict__ Og)
{
  // Double-buffered, XOR-swizzled tiles (16B chunk index ^= row&7)
  __shared__ short K_lds[2][64 * 128];   // [buf][kv][d]   2 x 16 KB
  __shared__ short V_T[2][128 * 64];     // [buf][d][kv]   2 x 16 KB

  const int tid  = threadIdx.x;
  const int lane = tid & 63;
  const int wave = tid >> 6;
  const int g    = lane >> 4;   // 0..3
  const int lo   = lane & 15;   // 0..15
  const int lo7  = lo & 7;

  const int bh = blockIdx.x;           // head fastest -> same-head cohorts resident
  const int qt = 15 - blockIdx.y;      // heavy (32-tile) blocks dispatched first
  const int q0 = qt * 128;

  const size_t base = (size_t)bh * 2048 * 128;
  const float* Qb = Qg + base;
  const float* Kb = Kg + base;
  const float* Vb = Vg + base;
  float*       Ob = Og + base;

  // staging index helpers
  const int vd   = tid & 31;
  const int vprb = tid >> 5;

  // --- Q fragments (scaled). B-frag role for swapped QK^T: col=lo, k=g*8+j ---
  bf16x8 qf[2][4];
  #pragma unroll
  for (int mt = 0; mt < 2; ++mt) {
    const int row = q0 + wave * 32 + mt * 16 + lo;
    const float* qr = Qb + (size_t)row * 128 + g * 8;
    #pragma unroll
    for (int kb = 0; kb < 4; ++kb) {
      f32x4 a = *(const f32x4*)(qr + kb * 32);
      f32x4 b = *(const f32x4*)(qr + kb * 32 + 4);
      bf16x8 w;
      #pragma unroll
      for (int jj = 0; jj < 4; ++jj) { w[jj] = f2bf(a[jj] * QSCALE); w[4 + jj] = f2bf(b[jj] * QSCALE); }
      qf[mt][kb] = w;
    }
  }

  float m_st[2] = {-3.0e38f, -3.0e38f};
  float l_st[2] = {0.0f, 0.0f};
  f32x4 o_acc[2][8];   // O^T: col=q(lo), row d = nd*16 + g*4 + r
  #pragma unroll
  for (int mt = 0; mt < 2; ++mt)
    #pragma unroll
    for (int nd = 0; nd < 8; ++nd) o_acc[mt][nd] = (f32x4){0.f, 0.f, 0.f, 0.f};

  const bool b1 = (g >> 1) & 1;
  const bool b0 = g & 1;

  const int ntiles = 2 * (qt + 1);

  // ---- prologue: stage tile 0 into buffer 0 (serial, once) ----
  {
    #pragma unroll
    for (int i = 0; i < 4; ++i) {
      const int idx = i * 256 + tid;
      const int kr = idx >> 4, dc16 = idx & 15;
      const float* src = Kb + (size_t)kr * 128 + dc16 * 8;
      f32x4 a = *(const f32x4*)src;
      f32x4 b = *(const f32x4*)(src + 4);
      bf16x8 w;
      #pragma unroll
      for (int jj = 0; jj < 4; ++jj) { w[jj] = f2bf(a[jj]); w[4 + jj] = f2bf(b[jj]); }
      *(bf16x8*)&K_lds[0][kr * 128 + ((dc16 ^ (kr & 7)) * 8)] = w;
    }
    #pragma unroll
    for (int i = 0; i < 4; ++i) {
      const int pr = vprb + i * 8;
      const float* v0 = Vb + (size_t)(2 * pr) * 128 + vd;
      #pragma unroll
      for (int jj = 0; jj < 4; ++jj) {
        const int row = vd + jj * 32;
        const unsigned pk = packbf(v0[jj * 32], v0[jj * 32 + 128]);
        *(unsigned*)&V_T[0][row * 64 + (((pr >> 2) ^ (row & 7)) * 8) + (pr & 3) * 2] = pk;
      }
    }
  }
  __syncthreads();

  int cur = 0;
  for (int t = 0; t < ntiles; ++t) {
    const int kv0 = t * 64;
    const short* Kc = K_lds[cur];
    const short* Vc = V_T[cur];
    short* Kn = K_lds[cur ^ 1];
    short* Vn = V_T[cur ^ 1];

    // ---- issue tile t+1 global loads NOW; latency hides under compute ----
    f32x4 kpa[4], kpb[4];
    float vp[4][4][2];
    const bool have_next = (t + 1 < ntiles);
    if (have_next) {
      const int nkv0 = kv0 + 64;
      #pragma unroll
      for (int i = 0; i < 4; ++i) {
        const int idx = i * 256 + tid;
        const int kr = idx >> 4, dc16 = idx & 15;
        const float* src = Kb + (size_t)(nkv0 + kr) * 128 + dc16 * 8;
        kpa[i] = *(const f32x4*)src;
        kpb[i] = *(const f32x4*)(src + 4);
      }
      #pragma unroll
      for (int i = 0; i < 4; ++i) {
        const int pr = vprb + i * 8;
        const float* v0 = Vb + (size_t)(nkv0 + 2 * pr) * 128 + vd;
        #pragma unroll
        for (int jj = 0; jj < 4; ++jj) { vp[i][jj][0] = v0[jj * 32]; vp[i][jj][1] = v0[jj * 32 + 128]; }
      }
    }
    // pin the load issue above this point (defeats the R3 load-sinking)
    __builtin_amdgcn_sched_barrier(0);

    if (kv0 <= q0 + wave * 32 + 31) {   // wave has unmasked work in this tile
      // ---- swapped QK^T: S^T = mfma(K, Q); lane holds S[q=lo][kv=nb*16+g*4+r] ----
      f32x4 s[2][4];
      #pragma unroll
      for (int mt = 0; mt < 2; ++mt)
        #pragma unroll
        for (int nb = 0; nb < 4; ++nb) s[mt][nb] = (f32x4){0.f, 0.f, 0.f, 0.f};

      __builtin_amdgcn_s_setprio(1);
      #pragma unroll
      for (int nb = 0; nb < 4; ++nb) {
        #pragma unroll
        for (int kb = 0; kb < 4; ++kb) {
          bf16x8 kf = *(const bf16x8*)&Kc[(nb * 16 + lo) * 128 + (((kb * 4 + g) ^ lo7) * 8)];
          s[0][nb] = __builtin_amdgcn_mfma_f32_16x16x32_bf16(kf, qf[0][kb], s[0][nb], 0, 0, 0);
          s[1][nb] = __builtin_amdgcn_mfma_f32_16x16x32_bf16(kf, qf[1][kb], s[1][nb], 0, 0, 0);
        }
      }
      __builtin_amdgcn_s_setprio(0);

      // ---- causal mask ----
      if (kv0 + 63 > q0 + wave * 32) {
        #pragma unroll
        for (int mt = 0; mt < 2; ++mt) {
          const int qrow = q0 + wave * 32 + mt * 16 + lo;
          #pragma unroll
          for (int nb = 0; nb < 4; ++nb) {
            const int kvb = kv0 + nb * 16 + g * 4;
            #pragma unroll
            for (int r = 0; r < 4; ++r)
              if (kvb + r > qrow) s[mt][nb][r] = -1.0e30f;
          }
        }
      }

      // ---- online softmax (scalar per lane) + P -> PV B-frags in registers ----
      bf16x8 pfrag[2][2];
      #pragma unroll
      for (int mt = 0; mt < 2; ++mt) {
        float tm = s[mt][0][0];
        #pragma unroll
        for (int nb = 0; nb < 4; ++nb)
          #pragma unroll
          for (int r = 0; r < 4; ++r) tm = fmaxf(tm, s[mt][nb][r]);
        tm = fmaxf(tm, __shfl_xor(tm, 16));
        tm = fmaxf(tm, __shfl_xor(tm, 32));
        const float mn = fmaxf(m_st[mt], tm);
        const float alpha = __builtin_amdgcn_exp2f((m_st[mt] - mn) * LOG2E);
        m_st[mt] = mn;

        float p[4][4];
        float ps = 0.0f;
        #pragma unroll
        for (int nb = 0; nb < 4; ++nb)
          #pragma unroll
          for (int r = 0; r < 4; ++r) {
            p[nb][r] = __builtin_amdgcn_exp2f((s[mt][nb][r] - mn) * LOG2E);
            ps += p[nb][r];
          }
        ps += __shfl_xor(ps, 16);
        ps += __shfl_xor(ps, 32);
        l_st[mt] = l_st[mt] * alpha + ps;
        #pragma unroll
        for (int nd = 0; nd < 8; ++nd)
          #pragma unroll
          for (int r = 0; r < 4; ++r) o_acc[mt][nd][r] *= alpha;

        // pack P pairs: pk[n1][n0][w] holds kv pair (n1*32+n0*16+g*4+2w, +1), q=lo
        unsigned pk[2][2][2];
        #pragma unroll
        for (int n1 = 0; n1 < 2; ++n1)
          #pragma unroll
          for (int n0 = 0; n0 < 2; ++n0)
            #pragma unroll
            for (int w = 0; w < 2; ++w)
              pk[n1][n0][w] = packbf(p[n1 * 2 + n0][2 * w], p[n1 * 2 + n0][2 * w + 1]);

        // butterfly: swap reg-bit n0 <-> lane-bit b1 (xor32), then rb <-> b0 (xor16)
        #pragma unroll
        for (int n1 = 0; n1 < 2; ++n1) {
          unsigned q2[2][2];
          #pragma unroll
          for (int w = 0; w < 2; ++w) {
            unsigned a = pk[n1][0][w], b = pk[n1][1][w];
            unsigned recv = __shfl_xor(b1 ? a : b, 32);
            unsigned r0 = b1 ? recv : a;
            unsigned r1 = b1 ? b : recv;
            unsigned recv2 = __shfl_xor(b0 ? r0 : r1, 16);
            q2[0][w] = b0 ? recv2 : r0;
            q2[1][w] = b0 ? r1 : recv2;
          }
          union { bf16x8 v; unsigned u[4]; } fb;
          fb.u[0] = q2[0][0]; fb.u[1] = q2[0][1]; fb.u[2] = q2[1][0]; fb.u[3] = q2[1][1];
          pfrag[mt][n1] = fb.v;   // B-frag: P^T[kv = n1*32 + g*8 + j][q = lo]
        }
      }

      // ---- PV: O^T += mfma(A=V^T, B=P^T) ----
      __builtin_amdgcn_s_setprio(1);
      #pragma unroll
      for (int kb2 = 0; kb2 < 2; ++kb2) {
        #pragma unroll
        for (int nd = 0; nd < 8; ++nd) {
          bf16x8 vf = *(const bf16x8*)&Vc[(nd * 16 + lo) * 64 + (((kb2 * 4 + g) ^ lo7) * 8)];
          o_acc[0][nd] = __builtin_amdgcn_mfma_f32_16x16x32_bf16(vf, pfrag[0][kb2], o_acc[0][nd], 0, 0, 0);
          o_acc[1][nd] = __builtin_amdgcn_mfma_f32_16x16x32_bf16(vf, pfrag[1][kb2], o_acc[1][nd], 0, 0, 0);
        }
      }
      __builtin_amdgcn_s_setprio(0);
    }

    // ---- convert prefetched regs -> LDS buf^1 (vmcnt wait lands here, after compute) ----
    if (have_next) {
      #pragma unroll
      for (int i = 0; i < 4; ++i) {
        const int idx = i * 256 + tid;
        const int kr = idx >> 4, dc16 = idx & 15;
        bf16x8 w;
        #pragma unroll
        for (int jj = 0; jj < 4; ++jj) { w[jj] = f2bf(kpa[i][jj]); w[4 + jj] = f2bf(kpb[i][jj]); }
        *(bf16x8*)&Kn[kr * 128 + ((dc16 ^ (kr & 7)) * 8)] = w;
      }
      #pragma unroll
      for (int i = 0; i < 4; ++i) {
        const int pr = vprb + i * 8;
        #pragma unroll
        for (int jj = 0; jj < 4; ++jj) {
          const int row = vd + jj * 32;
          const unsigned pk = packbf(vp[i][jj][0], vp[i][jj][1]);
          *(unsigned*)&Vn[row * 64 + (((pr >> 2) ^ (row & 7)) * 8) + (pr & 3) * 2] = pk;
        }
      }
    }
    __syncthreads();   // buf^1 ready; all waves done with buf cur
    cur ^= 1;
  }

  // ---- epilogue: O[q][d] = o_acc / l, f32x4 stores ----
  #pragma unroll
  for (int mt = 0; mt < 2; ++mt) {
    const float inv = 1.0f / l_st[mt];
    const int q = q0 + wave * 32 + mt * 16 + lo;
    #pragma unroll
    for (int nd = 0; nd < 8; ++nd) {
      f32x4 o;
      #pragma unroll
      for (int r = 0; r < 4; ++r) o[r] = o_acc[mt][nd][r] * inv;
      *(f32x4*)(Ob + (size_t)q * 128 + nd * 16 + g * 4) = o;
    }
  }
}

extern "C" void kernel_launch(void* const* d_in, const int* in_sizes, int n_in,
                              void* d_out, int out_size, void* d_ws, size_t ws_size,
                              hipStream_t stream) {
  const float* Q = (const float*)d_in[0];
  const float* K = (const float*)d_in[1];
  const float* V = (const float*)d_in[2];
  float* O = (float*)d_out;
  attn_fwd<<<dim3(64, 16), 256, 0, stream>>>(Q, K, V, O);
}

// Round 6
// 134.485 us; speedup vs baseline: 5.3411x; 1.1547x over previous
//
#include <hip/hip_runtime.h>
#include <hip/hip_bf16.h>

typedef __attribute__((ext_vector_type(8))) short bf16x8;
typedef __attribute__((ext_vector_type(4))) float f32x4;

#define LOG2E  1.4426950408889634f
#define QSCALE 0.08838834764831845f   // 1/sqrt(128)
#define DMTHR  8.0f                   // defer-max threshold (ln domain)

// native packed fp32->bf16 RNE convert (no builtin on gfx950; register-pure asm)
__device__ __forceinline__ unsigned cvt_pk_bf16(float lo, float hi) {
  unsigned r;
  asm("v_cvt_pk_bf16_f32 %0, %1, %2" : "=v"(r) : "v"(lo), "v"(hi));
  return r;
}

__global__ __launch_bounds__(256, 2) void attn_fwd(
    const float* __restrict__ Qg, const float* __restrict__ Kg,
    const float* __restrict__ Vg, float* __restrict__ Og)
{
  // Double-buffered, XOR-swizzled tiles (16B chunk index ^= row&7)
  __shared__ short K_lds[2][64 * 128];   // [buf][kv][d]   2 x 16 KB
  __shared__ short V_T[2][128 * 64];     // [buf][d][kv]   2 x 16 KB

  const int tid  = threadIdx.x;
  const int lane = tid & 63;
  const int wave = tid >> 6;
  const int g    = lane >> 4;   // 0..3
  const int lo   = lane & 15;   // 0..15
  const int lo7  = lo & 7;

  const int bh = blockIdx.x;           // head fastest -> same-head cohorts resident
  const int qt = 15 - blockIdx.y;      // heavy (32-tile) blocks dispatched first
  const int q0 = qt * 128;

  const size_t base = (size_t)bh * 2048 * 128;
  const float* Qb = Qg + base;
  const float* Kb = Kg + base;
  const float* Vb = Vg + base;
  float*       Ob = Og + base;

  const int vd   = tid & 31;
  const int vprb = tid >> 5;

  // --- Q fragments (scaled). B-frag role for swapped QK^T: col=lo, k=g*8+j ---
  bf16x8 qf[2][4];
  #pragma unroll
  for (int mt = 0; mt < 2; ++mt) {
    const int row = q0 + wave * 32 + mt * 16 + lo;
    const float* qr = Qb + (size_t)row * 128 + g * 8;
    #pragma unroll
    for (int kb = 0; kb < 4; ++kb) {
      f32x4 a = *(const f32x4*)(qr + kb * 32);
      f32x4 b = *(const f32x4*)(qr + kb * 32 + 4);
      union { bf16x8 v; unsigned u[4]; } w;
      w.u[0] = cvt_pk_bf16(a[0] * QSCALE, a[1] * QSCALE);
      w.u[1] = cvt_pk_bf16(a[2] * QSCALE, a[3] * QSCALE);
      w.u[2] = cvt_pk_bf16(b[0] * QSCALE, b[1] * QSCALE);
      w.u[3] = cvt_pk_bf16(b[2] * QSCALE, b[3] * QSCALE);
      qf[mt][kb] = w.v;
    }
  }

  float m_st[2] = {-3.0e38f, -3.0e38f};
  float l_st[2] = {0.0f, 0.0f};
  f32x4 o_acc[2][8];   // O^T: col=q(lo), row d = nd*16 + g*4 + r
  #pragma unroll
  for (int mt = 0; mt < 2; ++mt)
    #pragma unroll
    for (int nd = 0; nd < 8; ++nd) o_acc[mt][nd] = (f32x4){0.f, 0.f, 0.f, 0.f};

  const bool b1 = (g >> 1) & 1;
  const bool b0 = g & 1;

  const int ntiles = 2 * (qt + 1);

  // ---- prologue: stage tile 0 into buffer 0 ----
  {
    #pragma unroll
    for (int i = 0; i < 4; ++i) {
      const int idx = i * 256 + tid;
      const int kr = idx >> 4, dc16 = idx & 15;
      const float* src = Kb + (size_t)kr * 128 + dc16 * 8;
      f32x4 a = *(const f32x4*)src;
      f32x4 b = *(const f32x4*)(src + 4);
      union { bf16x8 v; unsigned u[4]; } w;
      w.u[0] = cvt_pk_bf16(a[0], a[1]);
      w.u[1] = cvt_pk_bf16(a[2], a[3]);
      w.u[2] = cvt_pk_bf16(b[0], b[1]);
      w.u[3] = cvt_pk_bf16(b[2], b[3]);
      *(bf16x8*)&K_lds[0][kr * 128 + ((dc16 ^ (kr & 7)) * 8)] = w.v;
    }
    #pragma unroll
    for (int i = 0; i < 4; ++i) {
      const int pr = vprb + i * 8;
      const float* v0 = Vb + (size_t)(2 * pr) * 128 + vd;
      #pragma unroll
      for (int jj = 0; jj < 4; ++jj) {
        const int row = vd + jj * 32;
        const unsigned pk = cvt_pk_bf16(v0[jj * 32], v0[jj * 32 + 128]);
        *(unsigned*)&V_T[0][row * 64 + (((pr >> 2) ^ (row & 7)) * 8) + (pr & 3) * 2] = pk;
      }
    }
  }
  __syncthreads();

  int cur = 0;
  for (int t = 0; t < ntiles; ++t) {
    const int kv0 = t * 64;
    const short* Kc = K_lds[cur];
    const short* Vc = V_T[cur];
    short* Kn = K_lds[cur ^ 1];
    short* Vn = V_T[cur ^ 1];

    // ---- issue tile t+1 global loads NOW; latency hides under compute ----
    f32x4 kpa[4], kpb[4];
    float vp[4][4][2];
    const bool have_next = (t + 1 < ntiles);
    if (have_next) {
      const int nkv0 = kv0 + 64;
      #pragma unroll
      for (int i = 0; i < 4; ++i) {
        const int idx = i * 256 + tid;
        const int kr = idx >> 4, dc16 = idx & 15;
        const float* src = Kb + (size_t)(nkv0 + kr) * 128 + dc16 * 8;
        kpa[i] = *(const f32x4*)src;
        kpb[i] = *(const f32x4*)(src + 4);
      }
      #pragma unroll
      for (int i = 0; i < 4; ++i) {
        const int pr = vprb + i * 8;
        const float* v0 = Vb + (size_t)(nkv0 + 2 * pr) * 128 + vd;
        #pragma unroll
        for (int jj = 0; jj < 4; ++jj) { vp[i][jj][0] = v0[jj * 32]; vp[i][jj][1] = v0[jj * 32 + 128]; }
      }
    }
    // pin the load issue above this point (defeats load-sinking)
    __builtin_amdgcn_sched_barrier(0);

    if (kv0 <= q0 + wave * 32 + 31) {   // wave has unmasked work in this tile
      // ---- swapped QK^T: S^T = mfma(K, Q); lane holds S[q=lo][kv=nb*16+g*4+r] ----
      f32x4 s[2][4];
      #pragma unroll
      for (int mt = 0; mt < 2; ++mt)
        #pragma unroll
        for (int nb = 0; nb < 4; ++nb) s[mt][nb] = (f32x4){0.f, 0.f, 0.f, 0.f};

      __builtin_amdgcn_s_setprio(1);
      #pragma unroll
      for (int nb = 0; nb < 4; ++nb) {
        #pragma unroll
        for (int kb = 0; kb < 4; ++kb) {
          bf16x8 kf = *(const bf16x8*)&Kc[(nb * 16 + lo) * 128 + (((kb * 4 + g) ^ lo7) * 8)];
          s[0][nb] = __builtin_amdgcn_mfma_f32_16x16x32_bf16(kf, qf[0][kb], s[0][nb], 0, 0, 0);
          s[1][nb] = __builtin_amdgcn_mfma_f32_16x16x32_bf16(kf, qf[1][kb], s[1][nb], 0, 0, 0);
        }
      }
      __builtin_amdgcn_s_setprio(0);

      // ---- causal mask ----
      if (kv0 + 63 > q0 + wave * 32) {
        #pragma unroll
        for (int mt = 0; mt < 2; ++mt) {
          const int qrow = q0 + wave * 32 + mt * 16 + lo;
          #pragma unroll
          for (int nb = 0; nb < 4; ++nb) {
            const int kvb = kv0 + nb * 16 + g * 4;
            #pragma unroll
            for (int r = 0; r < 4; ++r)
              if (kvb + r > qrow) s[mt][nb][r] = -1.0e30f;
          }
        }
      }

      // ---- online softmax (scalar per lane, defer-max) + P -> B-frags in regs ----
      bf16x8 pfrag[2][2];
      #pragma unroll
      for (int mt = 0; mt < 2; ++mt) {
        float tm = s[mt][0][0];
        #pragma unroll
        for (int nb = 0; nb < 4; ++nb)
          #pragma unroll
          for (int r = 0; r < 4; ++r) tm = fmaxf(tm, s[mt][nb][r]);
        tm = fmaxf(tm, __shfl_xor(tm, 16));
        tm = fmaxf(tm, __shfl_xor(tm, 32));

        // T13: only rescale when the running max actually grew past THR
        if (!__all(tm <= m_st[mt] + DMTHR)) {
          const float mn = fmaxf(m_st[mt], tm);
          const float alpha = __builtin_amdgcn_exp2f((m_st[mt] - mn) * LOG2E);
          m_st[mt] = mn;
          l_st[mt] *= alpha;
          #pragma unroll
          for (int nd = 0; nd < 8; ++nd)
            #pragma unroll
            for (int r = 0; r < 4; ++r) o_acc[mt][nd][r] *= alpha;
        }

        float p[4][4];
        float ps = 0.0f;
        #pragma unroll
        for (int nb = 0; nb < 4; ++nb)
          #pragma unroll
          for (int r = 0; r < 4; ++r) {
            p[nb][r] = __builtin_amdgcn_exp2f((s[mt][nb][r] - m_st[mt]) * LOG2E);
            ps += p[nb][r];
          }
        ps += __shfl_xor(ps, 16);
        ps += __shfl_xor(ps, 32);
        l_st[mt] += ps;

        // pack P pairs via cvt_pk: pk[n1][n0][w] = kv pair (n1*32+n0*16+g*4+2w, +1)
        unsigned pk[2][2][2];
        #pragma unroll
        for (int n1 = 0; n1 < 2; ++n1)
          #pragma unroll
          for (int n0 = 0; n0 < 2; ++n0)
            #pragma unroll
            for (int w = 0; w < 2; ++w)
              pk[n1][n0][w] = cvt_pk_bf16(p[n1 * 2 + n0][2 * w], p[n1 * 2 + n0][2 * w + 1]);

        // butterfly: swap reg-bit n0 <-> lane-bit b1 (xor32), then rb <-> b0 (xor16)
        #pragma unroll
        for (int n1 = 0; n1 < 2; ++n1) {
          unsigned q2[2][2];
          #pragma unroll
          for (int w = 0; w < 2; ++w) {
            unsigned a = pk[n1][0][w], b = pk[n1][1][w];
            unsigned recv = __shfl_xor(b1 ? a : b, 32);
            unsigned r0 = b1 ? recv : a;
            unsigned r1 = b1 ? b : recv;
            unsigned recv2 = __shfl_xor(b0 ? r0 : r1, 16);
            q2[0][w] = b0 ? recv2 : r0;
            q2[1][w] = b0 ? r1 : recv2;
          }
          union { bf16x8 v; unsigned u[4]; } fb;
          fb.u[0] = q2[0][0]; fb.u[1] = q2[0][1]; fb.u[2] = q2[1][0]; fb.u[3] = q2[1][1];
          pfrag[mt][n1] = fb.v;   // B-frag: P^T[kv = n1*32 + g*8 + j][q = lo]
        }
      }

      // ---- PV: O^T += mfma(A=V^T, B=P^T) ----
      __builtin_amdgcn_s_setprio(1);
      #pragma unroll
      for (int kb2 = 0; kb2 < 2; ++kb2) {
        #pragma unroll
        for (int nd = 0; nd < 8; ++nd) {
          bf16x8 vf = *(const bf16x8*)&Vc[(nd * 16 + lo) * 64 + (((kb2 * 4 + g) ^ lo7) * 8)];
          o_acc[0][nd] = __builtin_amdgcn_mfma_f32_16x16x32_bf16(vf, pfrag[0][kb2], o_acc[0][nd], 0, 0, 0);
          o_acc[1][nd] = __builtin_amdgcn_mfma_f32_16x16x32_bf16(vf, pfrag[1][kb2], o_acc[1][nd], 0, 0, 0);
        }
      }
      __builtin_amdgcn_s_setprio(0);
    }

    // ---- convert prefetched regs -> LDS buf^1 (vmcnt wait lands here) ----
    if (have_next) {
      #pragma unroll
      for (int i = 0; i < 4; ++i) {
        const int idx = i * 256 + tid;
        const int kr = idx >> 4, dc16 = idx & 15;
        union { bf16x8 v; unsigned u[4]; } w;
        w.u[0] = cvt_pk_bf16(kpa[i][0], kpa[i][1]);
        w.u[1] = cvt_pk_bf16(kpa[i][2], kpa[i][3]);
        w.u[2] = cvt_pk_bf16(kpb[i][0], kpb[i][1]);
        w.u[3] = cvt_pk_bf16(kpb[i][2], kpb[i][3]);
        *(bf16x8*)&Kn[kr * 128 + ((dc16 ^ (kr & 7)) * 8)] = w.v;
      }
      #pragma unroll
      for (int i = 0; i < 4; ++i) {
        const int pr = vprb + i * 8;
        #pragma unroll
        for (int jj = 0; jj < 4; ++jj) {
          const int row = vd + jj * 32;
          const unsigned pk = cvt_pk_bf16(vp[i][jj][0], vp[i][jj][1]);
          *(unsigned*)&Vn[row * 64 + (((pr >> 2) ^ (row & 7)) * 8) + (pr & 3) * 2] = pk;
        }
      }
    }
    __syncthreads();   // buf^1 ready; all waves done with buf cur
    cur ^= 1;
  }

  // ---- epilogue: O[q][d] = o_acc / l, f32x4 stores ----
  #pragma unroll
  for (int mt = 0; mt < 2; ++mt) {
    const float inv = 1.0f / l_st[mt];
    const int q = q0 + wave * 32 + mt * 16 + lo;
    #pragma unroll
    for (int nd = 0; nd < 8; ++nd) {
      f32x4 o;
      #pragma unroll
      for (int r = 0; r < 4; ++r) o[r] = o_acc[mt][nd][r] * inv;
      *(f32x4*)(Ob + (size_t)q * 128 + nd * 16 + g * 4) = o;
    }
  }
}

extern "C" void kernel_launch(void* const* d_in, const int* in_sizes, int n_in,
                              void* d_out, int out_size, void* d_ws, size_t ws_size,
                              hipStream_t stream) {
  const float* Q = (const float*)d_in[0];
  const float* K = (const float*)d_in[1];
  const float* V = (const float*)d_in[2];
  float* O = (float*)d_out;
  attn_fwd<<<dim3(64, 16), 256, 0, stream>>>(Q, K, V, O);
}